// Round 14
// baseline (142.815 us; speedup 1.0000x reference)
//
#include <hip/hip_runtime.h>
#include <hip/hip_bf16.h>
#include <math.h>

#define NC_   3072
#define NT_   1024
#define NTOK  4096
#define DD    256
#define NH    8
#define HDIM  32
#define NL    2
#define FFD   1024

typedef __attribute__((ext_vector_type(8))) short short8;
typedef __attribute__((ext_vector_type(4))) float f32x4;

#if __has_builtin(__builtin_amdgcn_exp2f)
#define EXP2(x) __builtin_amdgcn_exp2f(x)
#else
#define EXP2(x) exp2f(x)
#endif

#define QSCALE 0.25503482964f   // log2(e)/sqrt(32), folded into Q at GEMM epilogue

__device__ inline float bf2f(ushort u) { return __uint_as_float(((unsigned)u) << 16); }
__device__ inline ushort f2bf(float x) {
    __hip_bfloat16 h = __float2bfloat16(x);
    return *reinterpret_cast<ushort*>(&h);
}
__device__ inline void gload16(const void* g, void* l) {
    __builtin_amdgcn_global_load_lds(
        (const __attribute__((address_space(1))) void*)g,
        (__attribute__((address_space(3))) void*)l, 16, 0, 0);
}

// ---------------- weight convert + tanh stage (fused) ----------------
__global__ __launch_bounds__(256) void convert_kernel(
    const float* __restrict__ WQ, const float* __restrict__ WK,
    const float* __restrict__ WV, const float* __restrict__ WO,
    const float* __restrict__ W1, const float* __restrict__ W2,
    const float* __restrict__ bQ, const float* __restrict__ bK,
    const float* __restrict__ bV, const float* __restrict__ dW2,
    const float* __restrict__ y_context, const float* __restrict__ dec_W1,
    const float* __restrict__ dec_b1, ushort* __restrict__ tv,
    ushort* __restrict__ wbf, float* __restrict__ bqkv)
{
    int l = blockIdx.y;
    int idx = blockIdx.x * 256 + threadIdx.x;
    if (idx >= 852736) {                // tanh region (l==0 only)
        if (l != 0) return;
        int i2 = idx - 852736;          // 0..262143
        int m = i2 >> 6, k = (i2 & 63) * 4;
        float y = (m < NC_) ? y_context[m] : 0.f;
        ushort4 u;
        u.x = f2bf(tanhf(y * dec_W1[k+0] + dec_b1[k+0]));
        u.y = f2bf(tanhf(y * dec_W1[k+1] + dec_b1[k+1]));
        u.z = f2bf(tanhf(y * dec_W1[k+2] + dec_b1[k+2]));
        u.w = f2bf(tanhf(y * dec_W1[k+3] + dec_b1[k+3]));
        *(ushort4*)&tv[(size_t)i2 * 4] = u;
        return;
    }
    if (idx >= 787200) {                // shared dec_W2t (l==0 only)
        if (l != 0) return;
        int i = idx - 787200;           // 0..65535
        int n = i >> 8, k = i & 255;
        wbf[(size_t)2*786432 + i] = f2bf(dW2[(size_t)k*256 + n]);
        return;
    }
    if (idx >= 786432) {
        int i = idx - 786432;           // < 768
        float bv = (i < 256) ? bQ[l*256 + i]
                 : (i < 512) ? bK[l*256 + (i - 256)]
                             : bV[l*256 + (i - 512)];
        bqkv[l*768 + i] = bv;
        return;
    }
    float v;
    if (idx < 196608) {                 // WQKVt[768][256]
        int n = idx >> 8, k = idx & 255;
        v = (n < 256) ? WQ[(size_t)(l*256 + k)*256 + n]
          : (n < 512) ? WK[(size_t)(l*256 + k)*256 + (n-256)]
                      : WV[(size_t)(l*256 + k)*256 + (n-512)];
    } else if (idx < 262144) {          // WOt[256][256]
        int i = idx - 196608, n = i >> 8, k = i & 255;
        v = WO[(size_t)(l*256 + k)*256 + n];
    } else if (idx < 524288) {          // W1t[1024][256]
        int i = idx - 262144, n = i >> 8, k = i & 255;
        v = W1[(size_t)(l*256 + k)*1024 + n];
    } else {                            // W2t[256][1024]
        int i = idx - 524288, n = i >> 10, k = i & 1023;
        v = W2[(size_t)(l*1024 + k)*256 + n];
    }
    wbf[(size_t)l*786432 + idx] = f2bf(v);
}

// ---------------- bf16 MFMA GEMM 64x64 (4 waves) ----------------
// mode: 0=f32, 3=bf16+relu, 4=QKV split, 5=decorator
// qskip: mode-4 only — skip Q-columns (bx<4) for ctx rows (by<48); L1 never uses ctx-Q.
__global__ __launch_bounds__(256) void gemm_bf(
    const ushort* __restrict__ A, const ushort* __restrict__ Bt,
    const float* __restrict__ bias, void* __restrict__ Cv, void* __restrict__ Cv2,
    int M, int N, int K, int mode, int qskip,
    const float* __restrict__ xc, const float* __restrict__ ca,
    const float* __restrict__ cb, const float* __restrict__ lk)
{
    if (mode == 4 && qskip && blockIdx.x < 4 && blockIdx.y < 48) return;
    __shared__ ushort As[64*64];   // [64 m][64 k], XOR-swizzled: byte ^= (row&7)<<4
    __shared__ ushort Bs[64*64];
    int tid = threadIdx.x, lane = tid & 63, w = tid >> 6;
    int wm = w >> 1, wn = w & 1;
    int m0 = blockIdx.y * 64, n0 = blockIdx.x * 64;
    int col = lane & 15, grp = lane >> 4;
    f32x4 acc[2][2] = {};

    for (int k0 = 0; k0 < K; k0 += 64) {
        __syncthreads();
        #pragma unroll
        for (int s = 0; s < 2; ++s) {
            int i = tid + s*256;
            int r = i >> 3, j = i & 7;
            int kb = (j*16) ^ ((r & 7) << 4);    // pre-swizzled source byte offset
            gload16((const char*)(A  + (size_t)(m0 + r)*K + k0) + kb,
                    (char*)As + s*4096 + w*1024);
            gload16((const char*)(Bt + (size_t)(n0 + r)*K + k0) + kb,
                    (char*)Bs + s*4096 + w*1024);
        }
        __syncthreads();
        #pragma unroll
        for (int kk = 0; kk < 64; kk += 32) {
            short8 a[2], b[2];
            #pragma unroll
            for (int f = 0; f < 2; ++f) {
                int ra = wm*32 + f*16 + col;
                a[f] = *(const short8*)((char*)As + ra*128 + (((kk + grp*8)*2) ^ ((ra & 7) << 4)));
                int rb = wn*32 + f*16 + col;
                b[f] = *(const short8*)((char*)Bs + rb*128 + (((kk + grp*8)*2) ^ ((rb & 7) << 4)));
            }
            #pragma unroll
            for (int fm = 0; fm < 2; ++fm)
                #pragma unroll
                for (int fn = 0; fn < 2; ++fn)
                    acc[fm][fn] = __builtin_amdgcn_mfma_f32_16x16x32_bf16(a[fm], b[fn], acc[fm][fn], 0, 0, 0);
        }
    }
    float kap = (mode == 5) ? log1pf(expf(lk[0])) : 0.f;
    #pragma unroll
    for (int fm = 0; fm < 2; ++fm) {
        #pragma unroll
        for (int fn = 0; fn < 2; ++fn) {
            int ncol = n0 + wn*32 + fn*16 + col;
            int mbase = m0 + wm*32 + fm*16 + grp*4;
            float bs = bias[ncol];
            if (mode == 4 && ncol >= 512) {          // Vt transposed
                ushort* base = (ushort*)Cv2 - (size_t)512*M;
                ushort4 u;
                u.x = f2bf(acc[fm][fn][0] + bs); u.y = f2bf(acc[fm][fn][1] + bs);
                u.z = f2bf(acc[fm][fn][2] + bs); u.w = f2bf(acc[fm][fn][3] + bs);
                *(ushort4*)(base + (size_t)ncol*M + mbase) = u;
            } else if (mode == 4) {                  // Q (scaled) / K head-major
                int cc = ncol & 255, hh = cc >> 5, hd = cc & 31;
                ushort* base = (ushort*)Cv + ((ncol < 256) ? 0u : 1048576u);
                float sc = (ncol < 256) ? QSCALE : 1.f;
                #pragma unroll
                for (int r = 0; r < 4; ++r)
                    base[((size_t)hh*M + mbase + r)*HDIM + hd] = f2bf((acc[fm][fn][r] + bs) * sc);
            } else if (mode == 5) {                  // decorator epilogue
                #pragma unroll
                for (int r = 0; r < 4; ++r) {
                    int m = mbase + r;
                    float basev = (m < NC_) ? ca[(size_t)m*DD + ncol]
                                            : cb[(size_t)(m - NC_)*DD + ncol];
                    float wv = 0.f;
                    if (m < NC_) { float e = xc[m]; wv = e / (e + kap); }
                    float v = basev + wv * (acc[fm][fn][r] + bs);
                    ((float*)Cv)[(size_t)m*DD + ncol] = v;
                    ((ushort*)Cv2)[(size_t)m*DD + ncol] = f2bf(v);
                }
            } else {
                #pragma unroll
                for (int r = 0; r < 4; ++r) {
                    float v = acc[fm][fn][r] + bs;
                    if (mode == 3) v = fmaxf(v, 0.f);
                    if (mode == 0) ((float*)Cv)[(size_t)(mbase + r)*N + ncol] = v;
                    else           ((ushort*)Cv)[(size_t)(mbase + r)*N + ncol] = f2bf(v);
                }
            }
        }
    }
}

// ---------------- flash attention: 16 waves, 64 q/block, 128-key tiles ----------------
// No-max softmax (p = exp2(s)). K/V via global_load_lds, rule-#21 both-sides swizzle.
// 4-BUFFER 2-DEEP PIPELINE (T3/T4): load t+2 issued during tile t; steady-state wait
// is vmcnt(1) — one load stays in flight across the barrier (never drain to 0 mid-loop).
// Unroll-4 with literal buffer indices. P in registers; truncating bf16 P-pack (bias
// cancels in O = sum(PV)/sum(P)); lsum via ones-MFMA.
__global__ __launch_bounds__(1024, 8) void attn_kernel(
    const ushort* __restrict__ Qh, const ushort* __restrict__ Kh,
    const ushort* __restrict__ Vt, ushort* __restrict__ AO,
    float* __restrict__ pml, float* __restrict__ pacc, int l2mode)
{
    __shared__ __align__(16) char smem[65536];   // K bufs 0..3 @ 0/8192/16384/24576; V @ +32768
    __shared__ float cml[16][16];
    int tid = threadIdx.x;
    int w = tid >> 6, lane = tid & 63;
    int q = lane & 15, g = lane >> 4;
    int wq = w & 3, kh = w >> 2;
    int h = blockIdx.y;
    int zb = blockIdx.z;
    int q0   = l2mode ? (NC_ + blockIdx.x * 64) : (blockIdx.x * 64);
    int kbeg = l2mode ? zb * 1536 : 0;
    int do_self = l2mode ? (zb == 0) : (q0 >= NC_);
    int nt = l2mode ? 12 : (((q0 >= NC_) ? NC_ : NTOK) >> 7);   // 12/24/32: all %4 == 0

    // Q B-frag (pre-scaled, head-major)
    short8 bq = *(const short8*)&Qh[((size_t)h*NTOK + q0 + wq*16 + q)*HDIM + g*8];
    short8 ones;
    #pragma unroll
    for (int e = 0; e < 8; ++e) ones[e] = (short)0x3F80;   // bf16(1.0)

    f32x4 acc0 = {0.f,0.f,0.f,0.f}, acc1 = {0.f,0.f,0.f,0.f};
    f32x4 accl = {0.f,0.f,0.f,0.f};
    const f32x4 z = {0.f,0.f,0.f,0.f};

    // ---- staging source (per-lane, inverse-permuted + pre-swizzled) ----
    const ushort* src0;
    char* dst0;
    size_t sstep;
    if (w < 8) {        // K: wave w stages lines w*8..w*8+7 (1KB/buffer)
        int L  = (w << 3) + (lane >> 3);
        int s  = lane & 7;
        int e  = s ^ (L & 7);
        int r  = 2*L + (e >> 2);         // physical key-row 0..127
        int qt = e & 3;
        int ch = r >> 5, rr = r & 31;
        int hi = (rr >> 4) & 1, qp = rr & 15;
        int key = ch*32 + (((qp >> 2) << 3) | (hi << 2) | (qp & 3));   // inverse perm
        src0 = Kh + ((size_t)h*NTOK + kbeg + key)*HDIM + qt*8;
        sstep = (size_t)128*HDIM;
        dst0 = smem + w*1024;
    } else {            // V: wave u stages rows u*4..u*4+3 (1KB/buffer)
        int u = w - 8;
        int d = u*4 + (lane >> 4);
        int s = lane & 15;
        int e = (s & 8) | ((s ^ (d & 7)) & 7);
        src0 = Vt + ((size_t)(h*HDIM + d))*NTOK + kbeg + e*8;
        sstep = 128;
        dst0 = smem + 32768 + u*1024;
    }
    // prologue: stage tiles 0 and 1 (nt >= 12 always)
    gload16(src0, dst0);
    gload16(src0 + sstep, dst0 + 8192);
    asm volatile("s_waitcnt vmcnt(1)" ::: "memory");   // tile 0 landed; tile 1 in flight
    __builtin_amdgcn_s_barrier();
    __builtin_amdgcn_sched_barrier(0);

    // ---- compute read pointers (swizzled) ----
    const int L0 = kh*16 + (q >> 1);
    const char* kb0 = smem + L0*128 + (((((q & 1) << 2) + g) ^ (L0 & 7)) << 4);
    const int vslot = (kh << 2) + g;
    const int vsx = (vslot & 8) | ((vslot ^ (q & 7)) & 7);
    const char* vb0 = smem + 32768 + q*256 + (vsx << 4);
    const char* vb1 = vb0 + 16*256;

    // one tile: BUF literal 0..3; prefetch tile TT+2 into buffer (BUF+2)&3
#define ATTN_TILE(BUF, TT)                                                               \
    {                                                                                    \
        if ((TT) + 2 < nt)                                                               \
            gload16(src0 + (size_t)((TT)+2)*sstep, dst0 + (((BUF)+2)&3)*8192);           \
        short8 ka0 = *(const short8*)(kb0 + (BUF)*8192);                                 \
        short8 ka1 = *(const short8*)(kb0 + (BUF)*8192 + 1024);                          \
        __builtin_amdgcn_s_setprio(1);                                                   \
        f32x4 st0 = __builtin_amdgcn_mfma_f32_16x16x32_bf16(ka0, bq, z, 0, 0, 0);        \
        f32x4 st1 = __builtin_amdgcn_mfma_f32_16x16x32_bf16(ka1, bq, z, 0, 0, 0);        \
        __builtin_amdgcn_s_setprio(0);                                                   \
        float p0 = EXP2(st0[0]), p1 = EXP2(st0[1]);                                      \
        float p2 = EXP2(st0[2]), p3 = EXP2(st0[3]);                                      \
        float p4 = EXP2(st1[0]), p5 = EXP2(st1[1]);                                      \
        float p6 = EXP2(st1[2]), p7 = EXP2(st1[3]);                                      \
        uint4 pw;                                                                        \
        pw.x = (__float_as_uint(p0) >> 16) | (__float_as_uint(p1) & 0xFFFF0000u);        \
        pw.y = (__float_as_uint(p2) >> 16) | (__float_as_uint(p3) & 0xFFFF0000u);        \
        pw.z = (__float_as_uint(p4) >> 16) | (__float_as_uint(p5) & 0xFFFF0000u);        \
        pw.w = (__float_as_uint(p6) >> 16) | (__float_as_uint(p7) & 0xFFFF0000u);        \
        short8 pf = *(short8*)&pw;                                                       \
        short8 va0 = *(const short8*)(vb0 + (BUF)*8192);                                 \
        short8 va1 = *(const short8*)(vb1 + (BUF)*8192);                                 \
        __builtin_amdgcn_s_setprio(1);                                                   \
        acc0 = __builtin_amdgcn_mfma_f32_16x16x32_bf16(va0, pf, acc0, 0, 0, 0);          \
        acc1 = __builtin_amdgcn_mfma_f32_16x16x32_bf16(va1, pf, acc1, 0, 0, 0);          \
        accl = __builtin_amdgcn_mfma_f32_16x16x32_bf16(ones, pf, accl, 0, 0, 0);         \
        __builtin_amdgcn_s_setprio(0);                                                   \
        if ((TT) + 1 < nt) {                                                             \
            if ((TT) + 2 < nt)                                                           \
                asm volatile("s_waitcnt vmcnt(1)" ::: "memory");                         \
            else                                                                         \
                asm volatile("s_waitcnt vmcnt(0)" ::: "memory");                         \
            __builtin_amdgcn_s_barrier();                                                \
            __builtin_amdgcn_sched_barrier(0);                                           \
        }                                                                                \
    }

    for (int t = 0; t < nt; t += 4) {   // nt % 4 == 0 always
        ATTN_TILE(0, t)
        ATTN_TILE(1, t + 1)
        ATTN_TILE(2, t + 2)
        ATTN_TILE(3, t + 3)
    }
#undef ATTN_TILE

    float lsum = accl[0];   // full sum over this wave's keys (cross-group via MFMA)

    if (do_self && kh == 0) {   // self-key (structural mask), once per query
        int qg = q0 + wq*16 + q;
        short8 kv = *(const short8*)&Kh[((size_t)h*NTOK + qg)*HDIM + g*8];
        float d8 = 0.f;
        #pragma unroll
        for (int e = 0; e < 8; ++e) d8 += bf2f((ushort)bq[e]) * bf2f((ushort)kv[e]);
        d8 += __shfl_xor(d8, 16, 64);
        d8 += __shfl_xor(d8, 32, 64);    // already log2-scaled (Q pre-scaled)
        float pp = EXP2(d8);
        lsum += pp;
        #pragma unroll
        for (int r = 0; r < 4; ++r) {
            acc0[r] += pp * bf2f(Vt[(size_t)(h*HDIM + g*4 + r)*NTOK + qg]);
            acc1[r] += pp * bf2f(Vt[(size_t)(h*HDIM + 16 + g*4 + r)*NTOK + qg]);
        }
    }

    __syncthreads();                      // K/V tiles dead; reuse smem as combine buffer
    float* cacc = (float*)smem;           // [16][32][17] = 34816 B < 65536
    #pragma unroll
    for (int r = 0; r < 4; ++r) {
        cacc[(w*32 + g*4 + r)*17 + q]      = acc0[r];
        cacc[(w*32 + 16 + g*4 + r)*17 + q] = acc1[r];
    }
    if (g == 0) cml[w][q] = lsum;
    __syncthreads();

    if (w < 4) {   // merge over key-quarters {w, w+4, w+8, w+12}; q-group w (plain sums)
        float L = cml[w][q] + cml[w+4][q] + cml[w+8][q] + cml[w+12][q];
        if (!l2mode) {
            float inv = 1.f / L;
            ushort* dst = AO + (size_t)(q0 + w*16 + q)*DD + h*HDIM;
            ushort4 o0, o1;
            #pragma unroll
            for (int r = 0; r < 4; ++r) {
                int e0 = g*4 + r, e1 = 16 + g*4 + r;
                float O0 = cacc[(w*32+e0)*17+q] + cacc[((w+4)*32+e0)*17+q]
                         + cacc[((w+8)*32+e0)*17+q] + cacc[((w+12)*32+e0)*17+q];
                float O1 = cacc[(w*32+e1)*17+q] + cacc[((w+4)*32+e1)*17+q]
                         + cacc[((w+8)*32+e1)*17+q] + cacc[((w+12)*32+e1)*17+q];
                ((ushort*)&o0)[r] = f2bf(O0 * inv);
                ((ushort*)&o1)[r] = f2bf(O1 * inv);
            }
            *(ushort4*)(dst + g*4) = o0;
            *(ushort4*)(dst + 16 + g*4) = o1;
        } else {     // partial out: unnormalized O + l
            int qi = q0 - NC_ + w*16 + q;
            float* pa = pacc + (((size_t)zb*NH + h)*NT_ + qi)*32;
            #pragma unroll
            for (int r = 0; r < 4; ++r) {
                int e0 = g*4 + r, e1 = 16 + g*4 + r;
                pa[e0] = cacc[(w*32+e0)*17+q] + cacc[((w+4)*32+e0)*17+q]
                       + cacc[((w+8)*32+e0)*17+q] + cacc[((w+12)*32+e0)*17+q];
                pa[e1] = cacc[(w*32+e1)*17+q] + cacc[((w+4)*32+e1)*17+q]
                       + cacc[((w+8)*32+e1)*17+q] + cacc[((w+12)*32+e1)*17+q];
            }
            if (g == 0) pml[((size_t)zb*NH + h)*NT_ + qi] = L;
        }
    }
}

// ---------------- combine: merge of layer-2 attn partials -> AO (plain sums) ----------------
__global__ __launch_bounds__(256) void combine_kernel(
    const float* __restrict__ pml, const float* __restrict__ pacc, ushort* __restrict__ AO)
{
    int item = blockIdx.x * 8 + (threadIdx.x >> 5);   // 8192 items = 8 h x 1024 q
    int d = threadIdx.x & 31;
    int hh = item >> 10, qi = item & 1023;
    size_t i0 = ((size_t)0*NH + hh)*NT_ + qi;
    size_t i1 = ((size_t)1*NH + hh)*NT_ + qi;
    float inv = 1.f / (pml[i0] + pml[i1]);
    float O = pacc[i0*32 + d] + pacc[i1*32 + d];
    AO[(size_t)(NC_ + qi)*DD + hh*HDIM + d] = f2bf(O * inv);
}

// ---------------- layernorm: c = LN(c + delta)*g + b ; + bf16 copy; optional head ----
__global__ __launch_bounds__(256) void ln_kernel(
    float* __restrict__ c, const float* __restrict__ delta,
    const float* __restrict__ g, const float* __restrict__ b, ushort* __restrict__ cbf,
    const float* __restrict__ ow, const float* __restrict__ ob,
    const float* __restrict__ expo, float* __restrict__ out)
{
    int tid = threadIdx.x;
    int wid = tid >> 6, lane = tid & 63;
    int row = blockIdx.x * 4 + wid;
    float4 x  = *(const float4*)&c[(size_t)row*DD + lane*4];
    float4 dl = *(const float4*)&delta[(size_t)row*DD + lane*4];
    x.x += dl.x; x.y += dl.y; x.z += dl.z; x.w += dl.w;
    float s = x.x + x.y + x.z + x.w;
    #pragma unroll
    for (int off = 1; off < 64; off <<= 1) s += __shfl_xor(s, off, 64);
    float mean = s * (1.f/DD);
    float dx = x.x-mean, dy = x.y-mean, dz = x.z-mean, dw = x.w-mean;
    float v = dx*dx + dy*dy + dz*dz + dw*dw;
    #pragma unroll
    for (int off = 1; off < 64; off <<= 1) v += __shfl_xor(v, off, 64);
    float rstd = rsqrtf(v*(1.f/DD) + 1e-5f);
    float4 g4 = *(const float4*)&g[lane*4];
    float4 b4 = *(const float4*)&b[lane*4];
    float4 o;
    o.x = dx*rstd*g4.x + b4.x;
    o.y = dy*rstd*g4.y + b4.y;
    o.z = dz*rstd*g4.z + b4.z;
    o.w = dw*rstd*g4.w + b4.w;
    *(float4*)&c[(size_t)row*DD + lane*4] = o;
    ushort4 u;
    u.x = f2bf(o.x); u.y = f2bf(o.y); u.z = f2bf(o.z); u.w = f2bf(o.w);
    *(ushort4*)&cbf[(size_t)row*DD + lane*4] = u;
    if (ow != nullptr) {   // fused output head (target rows, local indexing)
        float4 wv = *(const float4*)&ow[lane*4];
        float ss = o.x*wv.x + o.y*wv.y + o.z*wv.z + o.w*wv.w;
        #pragma unroll
        for (int off = 1; off < 64; off <<= 1) ss += __shfl_xor(ss, off, 64);
        if (lane == 0) out[row] = expf(ss + ob[0]) * expo[row];
    }
}

extern "C" void kernel_launch(void* const* d_in, const int* in_sizes, int n_in,
                              void* d_out, int out_size, void* d_ws, size_t ws_size,
                              hipStream_t stream) {
    const float* c_ctx            = (const float*)d_in[0];
    const float* c_tgt            = (const float*)d_in[1];
    const float* y_context        = (const float*)d_in[2];
    const float* exposure_context = (const float*)d_in[3];
    const float* exposure_target  = (const float*)d_in[4];
    const float* dec_W1           = (const float*)d_in[5];
    const float* dec_b1           = (const float*)d_in[6];
    const float* dec_W2           = (const float*)d_in[7];
    const float* dec_b2           = (const float*)d_in[8];
    const float* log_kappa        = (const float*)d_in[9];
    const float* WQ               = (const float*)d_in[10];
    const float* bQ               = (const float*)d_in[11];
    const float* WK               = (const float*)d_in[12];
    const float* bK               = (const float*)d_in[13];
    const float* WV               = (const float*)d_in[14];
    const float* bV               = (const float*)d_in[15];
    const float* WO               = (const float*)d_in[16];
    const float* bO               = (const float*)d_in[17];
    const float* ln1_g            = (const float*)d_in[18];
    const float* ln1_b            = (const float*)d_in[19];
    const float* ln2_g            = (const float*)d_in[20];
    const float* ln2_b            = (const float*)d_in[21];
    const float* ffn_W1           = (const float*)d_in[22];
    const float* ffn_b1           = (const float*)d_in[23];
    const float* ffn_W2           = (const float*)d_in[24];
    const float* ffn_b2           = (const float*)d_in[25];
    const float* out_W            = (const float*)d_in[26];
    const float* out_b            = (const float*)d_in[27];
    float* out = (float*)d_out;

    float* ws = (float*)d_ws;
    float*  c    = ws;                          // 4096*256 f32
    float*  T    = ws + 1048576;                // 4096*256 f32 (also attn-L2 partial scratch)
    ushort* ub   = (ushort*)(ws + 2097152);
    ushort* c_bf = ub;                          // 4096*256 bf16
    ushort* Qh   = ub + 1048576;                // [8][4096][32] bf16, pre-scaled
    ushort* Khb  = ub + 2097152;                // [8][4096][32] bf16
    ushort* Vt   = ub + 3145728;                // [256][4096] bf16 (V transposed)
    ushort* AO   = ub + 4194304;                // 4096*256 bf16
    ushort* wbf  = ub + 5242880;                // 2*786432 bf16 weights + dec_W2t 65536
    ushort* wdec = wbf + 1572864;               // dec_W2t [256][256]
    float*  bqkv = (float*)(ub + 6881280);      // 2*768 f32
    ushort* tv   = AO;                          // 4096*256 bf16, dead after gemm5
    ushort* Hd   = Qh;                          // aliases Qh.. (dead then)
    float*  pml  = T;                           // [2][8][1024] f32
    float*  pacc = T + 16384;                   // [2][8][1024][32] f32

    convert_kernel<<<dim3(4355, 2), 256, 0, stream>>>(WQ, WK, WV, WO, ffn_W1, ffn_W2,
                                                      bQ, bK, bV, dec_W2,
                                                      y_context, dec_W1, dec_b1, tv,
                                                      wbf, bqkv);
    gemm_bf<<<dim3(4, 64), 256, 0, stream>>>(tv, wdec, dec_b2, c, c_bf, NTOK, DD, DD, 5, 0,
                                             exposure_context, c_ctx, c_tgt, log_kappa);
    // ---- layer 0 (full 4096 rows) ----
    {
        ushort* wl = wbf;
        gemm_bf<<<dim3(12, 64), 256, 0, stream>>>(c_bf, wl, bqkv, Qh, Vt, NTOK, 768, DD, 4, 0,
                                                  nullptr, nullptr, nullptr, nullptr);
        attn_kernel<<<dim3(64, NH, 1), 1024, 0, stream>>>(Qh, Khb, Vt, AO, nullptr, nullptr, 0);
        gemm_bf<<<dim3(4, 64),  256, 0, stream>>>(AO, wl + 196608, bO, T, nullptr, NTOK, DD, DD, 0, 0,
                                                  nullptr, nullptr, nullptr, nullptr);
        ln_kernel<<<NTOK/4, 256, 0, stream>>>(c, T, ln1_g, ln1_b, c_bf,
                                              nullptr, nullptr, nullptr, nullptr);
        gemm_bf<<<dim3(16, 64), 256, 0, stream>>>(c_bf, wl + 262144, ffn_b1, Hd, nullptr, NTOK, FFD, DD, 3, 0,
                                                  nullptr, nullptr, nullptr, nullptr);
        gemm_bf<<<dim3(4, 64),  256, 0, stream>>>(Hd, wl + 524288, ffn_b2, T, nullptr, NTOK, DD, FFD, 0, 0,
                                                  nullptr, nullptr, nullptr, nullptr);
        ln_kernel<<<NTOK/4, 256, 0, stream>>>(c, T, ln2_g, ln2_b, c_bf,
                                              nullptr, nullptr, nullptr, nullptr);
    }
    // ---- layer 1 (target rows only after QKV; ctx-Q blocks skipped) ----
    {
        ushort* wl = wbf + 786432;
        gemm_bf<<<dim3(12, 64), 256, 0, stream>>>(c_bf, wl, bqkv + 768, Qh, Vt, NTOK, 768, DD, 4, 1,
                                                  nullptr, nullptr, nullptr, nullptr);
        attn_kernel<<<dim3(16, NH, 2), 1024, 0, stream>>>(Qh, Khb, Vt, AO, pml, pacc, 1);
        combine_kernel<<<1024, 256, 0, stream>>>(pml, pacc, AO);
        gemm_bf<<<dim3(4, 16),  256, 0, stream>>>(AO + (size_t)NC_*DD, wl + 196608, bO + DD, T, nullptr,
                                                  NT_, DD, DD, 0, 0, nullptr, nullptr, nullptr, nullptr);
        ln_kernel<<<NT_/4, 256, 0, stream>>>(c + (size_t)NC_*DD, T, ln1_g + DD, ln1_b + DD,
                                             c_bf + (size_t)NC_*DD,
                                             nullptr, nullptr, nullptr, nullptr);
        gemm_bf<<<dim3(16, 16), 256, 0, stream>>>(c_bf + (size_t)NC_*DD, wl + 262144, ffn_b1 + FFD,
                                                  Hd, nullptr, NT_, FFD, DD, 3, 0,
                                                  nullptr, nullptr, nullptr, nullptr);
        gemm_bf<<<dim3(4, 16),  256, 0, stream>>>(Hd, wl + 524288, ffn_b2 + DD, T, nullptr,
                                                  NT_, DD, FFD, 0, 0, nullptr, nullptr, nullptr, nullptr);
        ln_kernel<<<NT_/4, 256, 0, stream>>>(c + (size_t)NC_*DD, T, ln2_g + DD, ln2_b + DD,
                                             c_bf + (size_t)NC_*DD,
                                             out_W, out_b, exposure_target, out);
    }
}